// Round 1
// baseline (788.852 us; speedup 1.0000x reference)
//
#include <hip/hip_runtime.h>

// Shapes (fixed by the reference): x (2,64,256,256), out (2,256,256,256)
#define EPSV 1e-5f

// ---------------------------------------------------------------------------
// K1: fused LayerNorm + dual projection (Wl, Wr) + mask. 8 rows per block.
// rows are flat (b,m,i); mask flat index == row index.
// ---------------------------------------------------------------------------
__global__ __launch_bounds__(256) void k_ln_proj(
    const float* __restrict__ x, const int* __restrict__ mask,
    const float* __restrict__ ln_w, const float* __restrict__ ln_b,
    const float* __restrict__ Wl, const float* __restrict__ bl,
    const float* __restrict__ Wr, const float* __restrict__ br,
    float* __restrict__ L, float* __restrict__ R)
{
    __shared__ __align__(16) float xs[8 * 256];
    __shared__ float mu_s[8], rs_s[8];
    const int tid = threadIdx.x;
    const int r0 = blockIdx.x * 8;

    // load 8 contiguous rows (coalesced)
    for (int t = tid; t < 2048; t += 256)
        xs[t] = x[r0 * 256 + t];
    __syncthreads();

    // mean/var: 32 threads per row
    {
        const int row = tid >> 5, lane = tid & 31;
        float s1 = 0.f, s2 = 0.f;
#pragma unroll
        for (int k = 0; k < 8; ++k) {
            float v = xs[row * 256 + lane + k * 32];
            s1 += v; s2 += v * v;
        }
#pragma unroll
        for (int off = 16; off > 0; off >>= 1) {
            s1 += __shfl_down(s1, off, 32);
            s2 += __shfl_down(s2, off, 32);
        }
        if (lane == 0) {
            float mu = s1 * (1.f / 256.f);
            float var = s2 * (1.f / 256.f) - mu * mu;
            mu_s[row] = mu;
            rs_s[row] = rsqrtf(var + EPSV);
        }
    }
    __syncthreads();

    // normalize in LDS
    for (int t = tid; t < 2048; t += 256) {
        int row = t >> 8, d = t & 255;
        xs[t] = (xs[t] - mu_s[row]) * rs_s[row] * ln_w[d] + ln_b[d];
    }
    __syncthreads();

    // projections: thread = output column h; 8 rows per thread
    const int h = tid;
    float accL[8], accR[8];
#pragma unroll
    for (int r = 0; r < 8; ++r) { accL[r] = 0.f; accR[r] = 0.f; }

    for (int d = 0; d < 256; d += 4) {
        float wl[4], wr[4];
#pragma unroll
        for (int k = 0; k < 4; ++k) {
            wl[k] = Wl[(d + k) * 256 + h];   // coalesced across threads
            wr[k] = Wr[(d + k) * 256 + h];
        }
#pragma unroll
        for (int r = 0; r < 8; ++r) {
            const float4 v = *reinterpret_cast<const float4*>(&xs[r * 256 + d]); // LDS broadcast
            accL[r] += v.x * wl[0] + v.y * wl[1] + v.z * wl[2] + v.w * wl[3];
            accR[r] += v.x * wr[0] + v.y * wr[1] + v.z * wr[2] + v.w * wr[3];
        }
    }

    const float blh = bl[h], brh = br[h];
#pragma unroll
    for (int r = 0; r < 8; ++r) {
        const int rr = r0 + r;
        const float mf = mask[rr] ? 1.f : 0.f;   // mask flat idx == row idx
        L[rr * 256 + h] = (accL[r] + blh) * mf;
        R[rr * 256 + h] = (accR[r] + brh) * mf;
    }
}

// ---------------------------------------------------------------------------
// Kcnt: scale[b,i,j] = 1 / (64 * (sum_m mask[b,m,i]*mask[b,m,j] + EPS))
// ---------------------------------------------------------------------------
__global__ __launch_bounds__(256) void k_cnt(const int* __restrict__ mask,
                                             float* __restrict__ scale)
{
    const int b = blockIdx.y, i = blockIdx.x, j = threadIdx.x;
    float c = 0.f;
    for (int m = 0; m < 64; ++m) {
        int mi = mask[(b * 64 + m) * 256 + i];
        int mj = mask[(b * 64 + m) * 256 + j];
        c += (mi && mj) ? 1.f : 0.f;
    }
    scale[(b * 256 + i) * 256 + j] = 1.f / (64.f * (c + EPSV));
}

// ---------------------------------------------------------------------------
// K2: outer[b,i,j,h] = scale[b,i,j] * sum_m L[b,m,i,h]*R[b,m,j,h]
// 8x8 (i,j) register tile per block, thread = h. Writes into d_out (staging).
// ---------------------------------------------------------------------------
__global__ __launch_bounds__(256) void k_outer(
    const float* __restrict__ L, const float* __restrict__ R,
    const float* __restrict__ scale, float* __restrict__ outbuf)
{
    const int h = threadIdx.x;
    const int j0 = blockIdx.x * 8, i0 = blockIdx.y * 8, b = blockIdx.z;

    float acc[8][8];
#pragma unroll
    for (int ii = 0; ii < 8; ++ii)
#pragma unroll
        for (int jj = 0; jj < 8; ++jj) acc[ii][jj] = 0.f;

    const float* Lb = L + b * (64 * 256 * 256);
    const float* Rb = R + b * (64 * 256 * 256);

    for (int m = 0; m < 64; ++m) {
        const float* Lm = Lb + m * (256 * 256) + h;
        const float* Rm = Rb + m * (256 * 256) + h;
        float lv[8], rv[8];
#pragma unroll
        for (int ii = 0; ii < 8; ++ii) lv[ii] = Lm[(i0 + ii) * 256];
#pragma unroll
        for (int jj = 0; jj < 8; ++jj) rv[jj] = Rm[(j0 + jj) * 256];
#pragma unroll
        for (int ii = 0; ii < 8; ++ii)
#pragma unroll
            for (int jj = 0; jj < 8; ++jj)
                acc[ii][jj] += lv[ii] * rv[jj];
    }

#pragma unroll
    for (int ii = 0; ii < 8; ++ii) {
#pragma unroll
        for (int jj = 0; jj < 8; ++jj) {
            const int ij = (b * 256 + i0 + ii) * 256 + (j0 + jj);
            outbuf[ij * 256 + h] = acc[ii][jj] * scale[ij];
        }
    }
}

// ---------------------------------------------------------------------------
// K3: in-place rows GEMM on d_out: row <- row @ Wo + bo. 32 rows per block,
// rows staged in LDS before overwrite (block-local read-before-write).
// ---------------------------------------------------------------------------
__global__ __launch_bounds__(256) void k_wo(
    float* __restrict__ io, const float* __restrict__ Wo,
    const float* __restrict__ bo)
{
    __shared__ __align__(16) float os[32 * 256];
    const int tid = threadIdx.x;
    const int r0 = blockIdx.x * 32;

    for (int t = tid; t < 32 * 256; t += 256)
        os[t] = io[r0 * 256 + t];
    __syncthreads();

    float acc[32];
#pragma unroll
    for (int r = 0; r < 32; ++r) acc[r] = 0.f;

    for (int h = 0; h < 256; h += 4) {
        const float w0 = Wo[(h + 0) * 256 + tid];
        const float w1 = Wo[(h + 1) * 256 + tid];
        const float w2 = Wo[(h + 2) * 256 + tid];
        const float w3 = Wo[(h + 3) * 256 + tid];
#pragma unroll
        for (int r = 0; r < 32; ++r) {
            const float4 o = *reinterpret_cast<const float4*>(&os[r * 256 + h]); // broadcast
            acc[r] += o.x * w0 + o.y * w1 + o.z * w2 + o.w * w3;
        }
    }

    const float bod = bo[tid];
#pragma unroll
    for (int r = 0; r < 32; ++r)
        io[(r0 + r) * 256 + tid] = acc[r] + bod;
}

// ---------------------------------------------------------------------------
extern "C" void kernel_launch(void* const* d_in, const int* in_sizes, int n_in,
                              void* d_out, int out_size, void* d_ws, size_t ws_size,
                              hipStream_t stream)
{
    const float* x    = (const float*)d_in[0];
    const int*   mask = (const int*)  d_in[1];
    const float* ln_w = (const float*)d_in[2];
    const float* ln_b = (const float*)d_in[3];
    const float* Wl   = (const float*)d_in[4];
    const float* bl   = (const float*)d_in[5];
    const float* Wr   = (const float*)d_in[6];
    const float* br   = (const float*)d_in[7];
    const float* Wo   = (const float*)d_in[8];
    const float* bo   = (const float*)d_in[9];

    float* out   = (float*)d_out;
    float* ws    = (float*)d_ws;
    float* L     = ws;                 // 2*64*256*256 = 8,388,608 floats
    float* R     = ws + 8388608;       // same size
    float* scale = ws + 16777216;      // 2*256*256 = 131,072 floats

    // 1) LayerNorm + projections + mask  (rows = b*m*i = 32768, 8 per block)
    k_ln_proj<<<4096, 256, 0, stream>>>(x, mask, ln_w, ln_b, Wl, bl, Wr, br, L, R);
    // 2) pair-count scales
    k_cnt<<<dim3(256, 2), 256, 0, stream>>>(mask, scale);
    // 3) outer contraction over m, scaled — staged into d_out
    k_outer<<<dim3(32, 32, 2), 256, 0, stream>>>(L, R, scale, out);
    // 4) in-place @ Wo + bo
    k_wo<<<4096, 256, 0, stream>>>(out, Wo, bo);
}

// Round 2
// 640.340 us; speedup vs baseline: 1.2319x; 1.2319x over previous
//
#include <hip/hip_runtime.h>

// Shapes (fixed by the reference): x (2,64,256,256), out (2,256,256,256)
#define EPSV 1e-5f

typedef short bf16x8 __attribute__((ext_vector_type(8)));
typedef float f32x4  __attribute__((ext_vector_type(4)));

__device__ __forceinline__ unsigned short f32_bf16(float f) {
    unsigned int u = __float_as_uint(f);
    u += 0x7fff + ((u >> 16) & 1);           // RNE
    return (unsigned short)(u >> 16);
}

// ---------------------------------------------------------------------------
// K1: fused LayerNorm + dual projection (Wl, Wr) + mask. 8 rows per block.
// ---------------------------------------------------------------------------
__global__ __launch_bounds__(256) void k_ln_proj(
    const float* __restrict__ x, const int* __restrict__ mask,
    const float* __restrict__ ln_w, const float* __restrict__ ln_b,
    const float* __restrict__ Wl, const float* __restrict__ bl,
    const float* __restrict__ Wr, const float* __restrict__ br,
    float* __restrict__ L, float* __restrict__ R)
{
    __shared__ __align__(16) float xs[8 * 256];
    __shared__ float mu_s[8], rs_s[8];
    const int tid = threadIdx.x;
    const int r0 = blockIdx.x * 8;

    for (int t = tid; t < 2048; t += 256)
        xs[t] = x[r0 * 256 + t];
    __syncthreads();

    {
        const int row = tid >> 5, lane = tid & 31;
        float s1 = 0.f, s2 = 0.f;
#pragma unroll
        for (int k = 0; k < 8; ++k) {
            float v = xs[row * 256 + lane + k * 32];
            s1 += v; s2 += v * v;
        }
#pragma unroll
        for (int off = 16; off > 0; off >>= 1) {
            s1 += __shfl_down(s1, off, 32);
            s2 += __shfl_down(s2, off, 32);
        }
        if (lane == 0) {
            float mu = s1 * (1.f / 256.f);
            float var = s2 * (1.f / 256.f) - mu * mu;
            mu_s[row] = mu;
            rs_s[row] = rsqrtf(var + EPSV);
        }
    }
    __syncthreads();

    for (int t = tid; t < 2048; t += 256) {
        int row = t >> 8, d = t & 255;
        xs[t] = (xs[t] - mu_s[row]) * rs_s[row] * ln_w[d] + ln_b[d];
    }
    __syncthreads();

    const int h = tid;
    float accL[8], accR[8];
#pragma unroll
    for (int r = 0; r < 8; ++r) { accL[r] = 0.f; accR[r] = 0.f; }

    for (int d = 0; d < 256; d += 4) {
        float wl[4], wr[4];
#pragma unroll
        for (int k = 0; k < 4; ++k) {
            wl[k] = Wl[(d + k) * 256 + h];
            wr[k] = Wr[(d + k) * 256 + h];
        }
#pragma unroll
        for (int r = 0; r < 8; ++r) {
            const float4 v = *reinterpret_cast<const float4*>(&xs[r * 256 + d]);
            accL[r] += v.x * wl[0] + v.y * wl[1] + v.z * wl[2] + v.w * wl[3];
            accR[r] += v.x * wr[0] + v.y * wr[1] + v.z * wr[2] + v.w * wr[3];
        }
    }

    const float blh = bl[h], brh = br[h];
#pragma unroll
    for (int r = 0; r < 8; ++r) {
        const int rr = r0 + r;
        const float mf = mask[rr] ? 1.f : 0.f;
        L[rr * 256 + h] = (accL[r] + blh) * mf;
        R[rr * 256 + h] = (accR[r] + brh) * mf;
    }
}

// ---------------------------------------------------------------------------
// Kcnt: scale[b,i,j] = 1 / (64 * (sum_m mask[b,m,i]*mask[b,m,j] + EPS))
// ---------------------------------------------------------------------------
__global__ __launch_bounds__(256) void k_cnt(const int* __restrict__ mask,
                                             float* __restrict__ scale)
{
    const int b = blockIdx.y, i = blockIdx.x, j = threadIdx.x;
    float c = 0.f;
    for (int m = 0; m < 64; ++m) {
        int mi = mask[(b * 64 + m) * 256 + i];
        int mj = mask[(b * 64 + m) * 256 + j];
        c += (mi && mj) ? 1.f : 0.f;
    }
    scale[(b * 256 + i) * 256 + j] = 1.f / (64.f * (c + EPSV));
}

// ---------------------------------------------------------------------------
// K2: outer[b,i,j,h] = scale[b,i,j] * sum_m L[b,m,i,h]*R[b,m,j,h]
// 8x8 (i,j) register tile per block, thread = h. Writes fp32 into d_out.
// ---------------------------------------------------------------------------
__global__ __launch_bounds__(256) void k_outer(
    const float* __restrict__ L, const float* __restrict__ R,
    const float* __restrict__ scale, float* __restrict__ outbuf)
{
    const int h = threadIdx.x;
    const int j0 = blockIdx.x * 8, i0 = blockIdx.y * 8, b = blockIdx.z;

    float acc[8][8];
#pragma unroll
    for (int ii = 0; ii < 8; ++ii)
#pragma unroll
        for (int jj = 0; jj < 8; ++jj) acc[ii][jj] = 0.f;

    const float* Lb = L + b * (64 * 256 * 256);
    const float* Rb = R + b * (64 * 256 * 256);

    for (int m = 0; m < 64; ++m) {
        const float* Lm = Lb + m * (256 * 256) + h;
        const float* Rm = Rb + m * (256 * 256) + h;
        float lv[8], rv[8];
#pragma unroll
        for (int ii = 0; ii < 8; ++ii) lv[ii] = Lm[(i0 + ii) * 256];
#pragma unroll
        for (int jj = 0; jj < 8; ++jj) rv[jj] = Rm[(j0 + jj) * 256];
#pragma unroll
        for (int ii = 0; ii < 8; ++ii)
#pragma unroll
            for (int jj = 0; jj < 8; ++jj)
                acc[ii][jj] += lv[ii] * rv[jj];
    }

#pragma unroll
    for (int ii = 0; ii < 8; ++ii) {
#pragma unroll
        for (int jj = 0; jj < 8; ++jj) {
            const int ij = (b * 256 + i0 + ii) * 256 + (j0 + jj);
            outbuf[ij * 256 + h] = acc[ii][jj] * scale[ij];
        }
    }
}

// ---------------------------------------------------------------------------
// Kpack: repack Wo (256x256 fp32, k-major) into bf16 MFMA B-fragment order.
// Fragment f = (kb, nt, lane): 8 bf16 = B[kb*32 + quad*8 + j][nt*16 + (lane&15)]
// stored contiguously at Wp + f*8. One thread per fragment (8192 threads).
// ---------------------------------------------------------------------------
__global__ __launch_bounds__(256) void k_pack_wo(
    const float* __restrict__ Wo, unsigned short* __restrict__ Wp)
{
    const int t = blockIdx.x * 256 + threadIdx.x;   // 0..8191
    const int lane = t & 63, nt = (t >> 6) & 15, kb = t >> 10;
    const int quad = lane >> 4;
    const int n = nt * 16 + (lane & 15);
    const int k0 = kb * 32 + quad * 8;
    unsigned short tmp[8];
#pragma unroll
    for (int j = 0; j < 8; ++j)
        tmp[j] = f32_bf16(Wo[(k0 + j) * 256 + n]);
    unsigned int* dst = (unsigned int*)Wp + t * 4;
#pragma unroll
    for (int p = 0; p < 4; ++p)
        dst[p] = (unsigned int)tmp[2 * p] | ((unsigned int)tmp[2 * p + 1] << 16);
}

// ---------------------------------------------------------------------------
// K3: in-place rows GEMM on d_out via bf16 MFMA: row <- bf16(row) @ bf16(Wo) + bo
// Block = 256 threads = 4 waves; 64 rows/block (16 rows/wave). K=256 in 8
// steps of 32. A: fp32 global -> in-register bf16 (each wave reads only its
// own rows, writes them at the end -> in-place safe). B: packed fragments
// staged through LDS (16 KB/chunk), ds_read_b128 per fragment.
// ---------------------------------------------------------------------------
__global__ __launch_bounds__(256) void k_wo_mfma(
    float* __restrict__ io, const unsigned short* __restrict__ Wp,
    const float* __restrict__ bo)
{
    __shared__ float4 bsh[1024];                    // 16 KB B-chunk
    const int tid = threadIdx.x;
    const int lane = tid & 63, wave = tid >> 6;
    const int quad = lane >> 4, mrow = lane & 15;
    const long R0 = (long)blockIdx.x * 64 + wave * 16;

    // Preload this lane's A rows (fp32) and convert to bf16 fragments.
    const float* arow = io + (R0 + mrow) * 256 + quad * 8;
    bf16x8 afr[8];
#pragma unroll
    for (int kb = 0; kb < 8; ++kb) {
        const float4 a0 = *reinterpret_cast<const float4*>(arow + kb * 32);
        const float4 a1 = *reinterpret_cast<const float4*>(arow + kb * 32 + 4);
        afr[kb][0] = (short)f32_bf16(a0.x); afr[kb][1] = (short)f32_bf16(a0.y);
        afr[kb][2] = (short)f32_bf16(a0.z); afr[kb][3] = (short)f32_bf16(a0.w);
        afr[kb][4] = (short)f32_bf16(a1.x); afr[kb][5] = (short)f32_bf16(a1.y);
        afr[kb][6] = (short)f32_bf16(a1.z); afr[kb][7] = (short)f32_bf16(a1.w);
    }

    f32x4 acc[16];
#pragma unroll
    for (int nt = 0; nt < 16; ++nt) acc[nt] = {0.f, 0.f, 0.f, 0.f};

    const float4* wpv = reinterpret_cast<const float4*>(Wp);
    for (int kb = 0; kb < 8; ++kb) {
        if (kb) __syncthreads();                    // prev chunk reads done
#pragma unroll
        for (int t = tid, it = 0; it < 4; ++it, t += 256)
            bsh[t] = wpv[kb * 1024 + t];
        __syncthreads();
        const bf16x8* bptr = reinterpret_cast<const bf16x8*>(bsh);
#pragma unroll
        for (int nt = 0; nt < 16; ++nt) {
            bf16x8 b = bptr[nt * 64 + lane];
            acc[nt] = __builtin_amdgcn_mfma_f32_16x16x32_bf16(afr[kb], b, acc[nt], 0, 0, 0);
        }
    }

    // Epilogue: C[row = quad*4 + r][col = lane&15] per n-tile; + bias; store.
#pragma unroll
    for (int nt = 0; nt < 16; ++nt) {
        const int col = nt * 16 + mrow;
        const float bov = bo[col];
#pragma unroll
        for (int r = 0; r < 4; ++r)
            io[(R0 + quad * 4 + r) * 256 + col] = acc[nt][r] + bov;
    }
}

// ---------------------------------------------------------------------------
extern "C" void kernel_launch(void* const* d_in, const int* in_sizes, int n_in,
                              void* d_out, int out_size, void* d_ws, size_t ws_size,
                              hipStream_t stream)
{
    const float* x    = (const float*)d_in[0];
    const int*   mask = (const int*)  d_in[1];
    const float* ln_w = (const float*)d_in[2];
    const float* ln_b = (const float*)d_in[3];
    const float* Wl   = (const float*)d_in[4];
    const float* bl   = (const float*)d_in[5];
    const float* Wr   = (const float*)d_in[6];
    const float* br   = (const float*)d_in[7];
    const float* Wo   = (const float*)d_in[8];
    const float* bo   = (const float*)d_in[9];

    float* out   = (float*)d_out;
    float* ws    = (float*)d_ws;
    float* L     = ws;                       // 8,388,608 floats
    float* R     = ws + 8388608;             // 8,388,608 floats
    float* scale = ws + 16777216;            // 131,072 floats
    unsigned short* Wp = (unsigned short*)(ws + 16908288);  // 65,536 bf16 (128 KB)

    k_ln_proj<<<4096, 256, 0, stream>>>(x, mask, ln_w, ln_b, Wl, bl, Wr, br, L, R);
    k_cnt<<<dim3(256, 2), 256, 0, stream>>>(mask, scale);
    k_pack_wo<<<32, 256, 0, stream>>>(Wo, Wp);
    k_outer<<<dim3(32, 32, 2), 256, 0, stream>>>(L, R, scale, out);
    k_wo_mfma<<<2048, 256, 0, stream>>>(out, Wp, bo);
}

// Round 3
// 453.453 us; speedup vs baseline: 1.7397x; 1.4121x over previous
//
#include <hip/hip_runtime.h>

// Shapes (fixed by the reference): x (2,64,256,256), out (2,256,256,256)
#define EPSV 1e-5f

typedef short bf16x8 __attribute__((ext_vector_type(8)));
typedef float f32x4  __attribute__((ext_vector_type(4)));

__device__ __forceinline__ unsigned int f32_bf16(float f) {
    unsigned int u = __float_as_uint(f);
    u += 0x7fff + ((u >> 16) & 1);           // RNE
    return u >> 16;
}
__device__ __forceinline__ float bf16_f32(unsigned short s) {
    return __uint_as_float(((unsigned int)s) << 16);
}

// ---------------------------------------------------------------------------
// K1: fused LayerNorm + dual projection (Wl, Wr) + mask -> bf16 L, R.
// 8 rows per block, thread = output column h.
// ---------------------------------------------------------------------------
__global__ __launch_bounds__(256) void k_ln_proj(
    const float* __restrict__ x, const int* __restrict__ mask,
    const float* __restrict__ ln_w, const float* __restrict__ ln_b,
    const float* __restrict__ Wl, const float* __restrict__ bl,
    const float* __restrict__ Wr, const float* __restrict__ br,
    unsigned short* __restrict__ L, unsigned short* __restrict__ R)
{
    __shared__ __align__(16) float xs[8 * 256];
    __shared__ float mu_s[8], rs_s[8];
    const int tid = threadIdx.x;
    const int r0 = blockIdx.x * 8;

    for (int t = tid; t < 2048; t += 256)
        xs[t] = x[r0 * 256 + t];
    __syncthreads();

    {
        const int row = tid >> 5, lane = tid & 31;
        float s1 = 0.f, s2 = 0.f;
#pragma unroll
        for (int k = 0; k < 8; ++k) {
            float v = xs[row * 256 + lane + k * 32];
            s1 += v; s2 += v * v;
        }
#pragma unroll
        for (int off = 16; off > 0; off >>= 1) {
            s1 += __shfl_down(s1, off, 32);
            s2 += __shfl_down(s2, off, 32);
        }
        if (lane == 0) {
            float mu = s1 * (1.f / 256.f);
            float var = s2 * (1.f / 256.f) - mu * mu;
            mu_s[row] = mu;
            rs_s[row] = rsqrtf(var + EPSV);
        }
    }
    __syncthreads();

    for (int t = tid; t < 2048; t += 256) {
        int row = t >> 8, d = t & 255;
        xs[t] = (xs[t] - mu_s[row]) * rs_s[row] * ln_w[d] + ln_b[d];
    }
    __syncthreads();

    const int h = tid;
    float accL[8], accR[8];
#pragma unroll
    for (int r = 0; r < 8; ++r) { accL[r] = 0.f; accR[r] = 0.f; }

    for (int d = 0; d < 256; d += 4) {
        float wl[4], wr[4];
#pragma unroll
        for (int k = 0; k < 4; ++k) {
            wl[k] = Wl[(d + k) * 256 + h];
            wr[k] = Wr[(d + k) * 256 + h];
        }
#pragma unroll
        for (int r = 0; r < 8; ++r) {
            const float4 v = *reinterpret_cast<const float4*>(&xs[r * 256 + d]);
            accL[r] += v.x * wl[0] + v.y * wl[1] + v.z * wl[2] + v.w * wl[3];
            accR[r] += v.x * wr[0] + v.y * wr[1] + v.z * wr[2] + v.w * wr[3];
        }
    }

    const float blh = bl[h], brh = br[h];
#pragma unroll
    for (int r = 0; r < 8; ++r) {
        const int rr = r0 + r;
        const float mf = mask[rr] ? 1.f : 0.f;
        L[rr * 256 + h] = (unsigned short)f32_bf16((accL[r] + blh) * mf);
        R[rr * 256 + h] = (unsigned short)f32_bf16((accR[r] + brh) * mf);
    }
}

// ---------------------------------------------------------------------------
// Kcnt: scale[b,i,j] = 1 / (64 * (sum_m mask[b,m,i]*mask[b,m,j] + EPS))
// ---------------------------------------------------------------------------
__global__ __launch_bounds__(256) void k_cnt(const int* __restrict__ mask,
                                             float* __restrict__ scale)
{
    const int b = blockIdx.y, i = blockIdx.x, j = threadIdx.x;
    float c = 0.f;
    for (int m = 0; m < 64; ++m) {
        int mi = mask[(b * 64 + m) * 256 + i];
        int mj = mask[(b * 64 + m) * 256 + j];
        c += (mi && mj) ? 1.f : 0.f;
    }
    scale[(b * 256 + i) * 256 + j] = 1.f / (64.f * (c + EPSV));
}

// ---------------------------------------------------------------------------
// K2: outer[b,i,j,h] = scale[b,i,j] * sum_m L[b,m,i,h]*R[b,m,j,h]
// bf16 L/R inputs, fp32 accumulate, fp32 output staged in d_out.
// 8x8 (i,j) register tile per block, thread = h.
// ---------------------------------------------------------------------------
__global__ __launch_bounds__(256) void k_outer(
    const unsigned short* __restrict__ L, const unsigned short* __restrict__ R,
    const float* __restrict__ scale, float* __restrict__ outbuf)
{
    const int h = threadIdx.x;
    const int j0 = blockIdx.x * 8, i0 = blockIdx.y * 8, b = blockIdx.z;

    float acc[8][8];
#pragma unroll
    for (int ii = 0; ii < 8; ++ii)
#pragma unroll
        for (int jj = 0; jj < 8; ++jj) acc[ii][jj] = 0.f;

    const unsigned short* Lb = L + (size_t)b * (64 * 256 * 256);
    const unsigned short* Rb = R + (size_t)b * (64 * 256 * 256);

    for (int m = 0; m < 64; ++m) {
        const unsigned short* Lm = Lb + m * (256 * 256) + h;
        const unsigned short* Rm = Rb + m * (256 * 256) + h;
        float lv[8], rv[8];
#pragma unroll
        for (int ii = 0; ii < 8; ++ii) lv[ii] = bf16_f32(Lm[(i0 + ii) * 256]);
#pragma unroll
        for (int jj = 0; jj < 8; ++jj) rv[jj] = bf16_f32(Rm[(j0 + jj) * 256]);
#pragma unroll
        for (int ii = 0; ii < 8; ++ii)
#pragma unroll
            for (int jj = 0; jj < 8; ++jj)
                acc[ii][jj] += lv[ii] * rv[jj];
    }

#pragma unroll
    for (int ii = 0; ii < 8; ++ii) {
#pragma unroll
        for (int jj = 0; jj < 8; ++jj) {
            const int ij = (b * 256 + i0 + ii) * 256 + (j0 + jj);
            outbuf[(size_t)ij * 256 + h] = acc[ii][jj] * scale[ij];
        }
    }
}

// ---------------------------------------------------------------------------
// Kpack: repack Wo (256x256 fp32, k-major) into bf16 MFMA B-fragment order.
// Fragment f = (kb, nt, lane): 8 bf16 = B[kb*32 + quad*8 + j][nt*16 + (lane&15)]
// ---------------------------------------------------------------------------
__global__ __launch_bounds__(256) void k_pack_wo(
    const float* __restrict__ Wo, unsigned short* __restrict__ Wp)
{
    const int t = blockIdx.x * 256 + threadIdx.x;   // 0..8191
    const int lane = t & 63, nt = (t >> 6) & 15, kb = t >> 10;
    const int quad = lane >> 4;
    const int n = nt * 16 + (lane & 15);
    const int k0 = kb * 32 + quad * 8;
    unsigned int p[4];
#pragma unroll
    for (int pp = 0; pp < 4; ++pp) {
        unsigned int lo = f32_bf16(Wo[(k0 + 2 * pp) * 256 + n]);
        unsigned int hi = f32_bf16(Wo[(k0 + 2 * pp + 1) * 256 + n]);
        p[pp] = lo | (hi << 16);
    }
    unsigned int* dst = (unsigned int*)Wp + t * 4;
#pragma unroll
    for (int pp = 0; pp < 4; ++pp) dst[pp] = p[pp];
}

// ---------------------------------------------------------------------------
// K3: in-place rows GEMM on d_out via bf16 MFMA: row <- bf16(row) @ bf16(Wo) + bo
// 64 rows/block (4 waves x 16 rows). A-tile staged fp32->bf16 into LDS with
// fully coalesced float4 loads; rows padded to 264 ushorts (16B-aligned,
// breaks bank-aliasing). A-fragments via ds_read_b128. B staged in 16KB
// chunks from pre-packed Wp. In-place safe: block reads only rows it writes,
// reads complete (sync) before stores.
// ---------------------------------------------------------------------------
__global__ __launch_bounds__(256) void k_wo_mfma(
    float* __restrict__ io, const unsigned short* __restrict__ Wp,
    const float* __restrict__ bo)
{
    __shared__ __align__(16) unsigned short ash[64 * 264];   // 33792 B
    __shared__ float4 bsh[1024];                             // 16384 B
    const int tid = threadIdx.x;
    const int lane = tid & 63, wave = tid >> 6;
    const int quad = lane >> 4, mrow = lane & 15;
    const long r0 = (long)blockIdx.x * 64;

    // Stage A: 64 rows x 256 fp32 -> bf16 LDS, coalesced.
#pragma unroll
    for (int it = 0; it < 8; ++it) {
        const int c = tid + it * 256;          // chunk of 8 floats
        const int row = c >> 5, col = (c & 31) * 8;
        const float* src = io + (r0 + row) * 256 + col;
        const float4 a0 = *reinterpret_cast<const float4*>(src);
        const float4 a1 = *reinterpret_cast<const float4*>(src + 4);
        uint4 p;
        p.x = f32_bf16(a0.x) | (f32_bf16(a0.y) << 16);
        p.y = f32_bf16(a0.z) | (f32_bf16(a0.w) << 16);
        p.z = f32_bf16(a1.x) | (f32_bf16(a1.y) << 16);
        p.w = f32_bf16(a1.z) | (f32_bf16(a1.w) << 16);
        *reinterpret_cast<uint4*>(&ash[row * 264 + col]) = p;
    }

    f32x4 acc[16];
#pragma unroll
    for (int nt = 0; nt < 16; ++nt) acc[nt] = {0.f, 0.f, 0.f, 0.f};

    const float4* wpv = reinterpret_cast<const float4*>(Wp);
    const int arow = wave * 16 + mrow;

    for (int kb = 0; kb < 8; ++kb) {
        if (kb) __syncthreads();               // prev chunk reads done
#pragma unroll
        for (int it = 0; it < 4; ++it)
            bsh[tid + it * 256] = wpv[kb * 1024 + tid + it * 256];
        __syncthreads();                       // covers A-staging (kb==0) + bsh

        const bf16x8 afr = *reinterpret_cast<const bf16x8*>(
            &ash[arow * 264 + kb * 32 + quad * 8]);
        const bf16x8* bptr = reinterpret_cast<const bf16x8*>(bsh);
#pragma unroll
        for (int nt = 0; nt < 16; ++nt) {
            bf16x8 b = bptr[nt * 64 + lane];
            acc[nt] = __builtin_amdgcn_mfma_f32_16x16x32_bf16(afr, b, acc[nt], 0, 0, 0);
        }
    }

    // Epilogue: C[row = quad*4 + r][col = nt*16 + mrow]; + bias; store.
#pragma unroll
    for (int nt = 0; nt < 16; ++nt) {
        const int col = nt * 16 + mrow;
        const float bov = bo[col];
#pragma unroll
        for (int r = 0; r < 4; ++r)
            io[(r0 + wave * 16 + quad * 4 + r) * 256 + col] = acc[nt][r] + bov;
    }
}

// ---------------------------------------------------------------------------
extern "C" void kernel_launch(void* const* d_in, const int* in_sizes, int n_in,
                              void* d_out, int out_size, void* d_ws, size_t ws_size,
                              hipStream_t stream)
{
    const float* x    = (const float*)d_in[0];
    const int*   mask = (const int*)  d_in[1];
    const float* ln_w = (const float*)d_in[2];
    const float* ln_b = (const float*)d_in[3];
    const float* Wl   = (const float*)d_in[4];
    const float* bl   = (const float*)d_in[5];
    const float* Wr   = (const float*)d_in[6];
    const float* br   = (const float*)d_in[7];
    const float* Wo   = (const float*)d_in[8];
    const float* bo   = (const float*)d_in[9];

    float* out = (float*)d_out;
    char*  ws  = (char*)d_ws;
    unsigned short* L     = (unsigned short*)(ws);                     // 16 MB
    unsigned short* R     = (unsigned short*)(ws + 16777216);          // 16 MB
    float*          scale = (float*)         (ws + 33554432);          // 512 KB
    unsigned short* Wp    = (unsigned short*)(ws + 34078720);          // 128 KB

    k_ln_proj<<<4096, 256, 0, stream>>>(x, mask, ln_w, ln_b, Wl, bl, Wr, br, L, R);
    k_cnt<<<dim3(256, 2), 256, 0, stream>>>(mask, scale);
    k_pack_wo<<<32, 256, 0, stream>>>(Wo, Wp);
    k_outer<<<dim3(32, 32, 2), 256, 0, stream>>>(L, R, scale, out);
    k_wo_mfma<<<2048, 256, 0, stream>>>(out, Wp, bo);
}

// Round 4
// 338.385 us; speedup vs baseline: 2.3312x; 1.3400x over previous
//
#include <hip/hip_runtime.h>

// Shapes (fixed by the reference): x (2,64,256,256), out (2,256,256,256)
#define EPSV 1e-5f

typedef short bf16x8 __attribute__((ext_vector_type(8)));
typedef float f32x4  __attribute__((ext_vector_type(4)));

__device__ __forceinline__ unsigned int f32_bf16(float f) {
    unsigned int u = __float_as_uint(f);
    u += 0x7fff + ((u >> 16) & 1);           // RNE
    return u >> 16;
}
__device__ __forceinline__ float bf16_f32(unsigned short s) {
    return __uint_as_float(((unsigned int)s) << 16);
}

// ---------------------------------------------------------------------------
// K0: LayerNorm -> bf16 xn. 8 rows/block, 32 lanes per row, register-resident.
// ---------------------------------------------------------------------------
__global__ __launch_bounds__(256) void k_ln(
    const float* __restrict__ x, const float* __restrict__ ln_w,
    const float* __restrict__ ln_b, unsigned short* __restrict__ xn)
{
    const int tid = threadIdx.x;
    const size_t row = (size_t)blockIdx.x * 8 + (tid >> 5);
    const int c0 = (tid & 31) * 8;

    const float* src = x + row * 256 + c0;
    const float4 a0 = *reinterpret_cast<const float4*>(src);
    const float4 a1 = *reinterpret_cast<const float4*>(src + 4);
    float v[8] = {a0.x, a0.y, a0.z, a0.w, a1.x, a1.y, a1.z, a1.w};

    float s1 = 0.f, s2 = 0.f;
#pragma unroll
    for (int k = 0; k < 8; ++k) { s1 += v[k]; s2 += v[k] * v[k]; }
#pragma unroll
    for (int m = 16; m > 0; m >>= 1) {
        s1 += __shfl_xor(s1, m, 32);
        s2 += __shfl_xor(s2, m, 32);
    }
    const float mu = s1 * (1.f / 256.f);
    const float rs = rsqrtf(s2 * (1.f / 256.f) - mu * mu + EPSV);

    const float4 w0 = *reinterpret_cast<const float4*>(ln_w + c0);
    const float4 w1 = *reinterpret_cast<const float4*>(ln_w + c0 + 4);
    const float4 b0 = *reinterpret_cast<const float4*>(ln_b + c0);
    const float4 b1 = *reinterpret_cast<const float4*>(ln_b + c0 + 4);
    const float wv[8] = {w0.x, w0.y, w0.z, w0.w, w1.x, w1.y, w1.z, w1.w};
    const float bv[8] = {b0.x, b0.y, b0.z, b0.w, b1.x, b1.y, b1.z, b1.w};

    uint4 p;
    unsigned int y[8];
#pragma unroll
    for (int k = 0; k < 8; ++k)
        y[k] = f32_bf16((v[k] - mu) * rs * wv[k] + bv[k]);
    p.x = y[0] | (y[1] << 16);
    p.y = y[2] | (y[3] << 16);
    p.z = y[4] | (y[5] << 16);
    p.w = y[6] | (y[7] << 16);
    *reinterpret_cast<uint4*>(xn + row * 256 + c0) = p;
}

// ---------------------------------------------------------------------------
// Kcnt: scale[b,i,j] = 1 / (64 * (sum_m mask[b,m,i]*mask[b,m,j] + EPS))
// ---------------------------------------------------------------------------
__global__ __launch_bounds__(256) void k_cnt(const int* __restrict__ mask,
                                             float* __restrict__ scale)
{
    const int b = blockIdx.y, i = blockIdx.x, j = threadIdx.x;
    float c = 0.f;
    for (int m = 0; m < 64; ++m) {
        int mi = mask[(b * 64 + m) * 256 + i];
        int mj = mask[(b * 64 + m) * 256 + j];
        c += (mi && mj) ? 1.f : 0.f;
    }
    scale[(b * 256 + i) * 256 + j] = 1.f / (64.f * (c + EPSV));
}

// ---------------------------------------------------------------------------
// Kpack_wlr: pack Wl (nt 0..15) and Wr (nt 16..31) into MFMA B-fragment order.
// Fragment f = (kb, nt, lane): 8 bf16 = W[kb*32 + quad*8 + j][(nt&15)*16 + (lane&15)]
// ---------------------------------------------------------------------------
__global__ __launch_bounds__(256) void k_pack_wlr(
    const float* __restrict__ Wl, const float* __restrict__ Wr,
    unsigned short* __restrict__ Wp2)
{
    const int t = blockIdx.x * 256 + threadIdx.x;   // 0..16383
    const int lane = t & 63, nt = (t >> 6) & 31, kb = t >> 11;
    const int quad = lane >> 4;
    const float* W = (nt < 16) ? Wl : Wr;
    const int n = (nt & 15) * 16 + (lane & 15);
    const int k0 = kb * 32 + quad * 8;
    unsigned int p[4];
#pragma unroll
    for (int pp = 0; pp < 4; ++pp) {
        unsigned int lo = f32_bf16(W[(k0 + 2 * pp) * 256 + n]);
        unsigned int hi = f32_bf16(W[(k0 + 2 * pp + 1) * 256 + n]);
        p[pp] = lo | (hi << 16);
    }
    unsigned int* dst = (unsigned int*)Wp2 + t * 4;
#pragma unroll
    for (int pp = 0; pp < 4; ++pp) dst[pp] = p[pp];
}

// ---------------------------------------------------------------------------
// Kpack_wo: same packing for Wo (N=256, nt 0..15).
// ---------------------------------------------------------------------------
__global__ __launch_bounds__(256) void k_pack_wo(
    const float* __restrict__ Wo, unsigned short* __restrict__ Wp)
{
    const int t = blockIdx.x * 256 + threadIdx.x;   // 0..8191
    const int lane = t & 63, nt = (t >> 6) & 15, kb = t >> 10;
    const int quad = lane >> 4;
    const int n = nt * 16 + (lane & 15);
    const int k0 = kb * 32 + quad * 8;
    unsigned int p[4];
#pragma unroll
    for (int pp = 0; pp < 4; ++pp) {
        unsigned int lo = f32_bf16(Wo[(k0 + 2 * pp) * 256 + n]);
        unsigned int hi = f32_bf16(Wo[(k0 + 2 * pp + 1) * 256 + n]);
        p[pp] = lo | (hi << 16);
    }
    unsigned int* dst = (unsigned int*)Wp + t * 4;
#pragma unroll
    for (int pp = 0; pp < 4; ++pp) dst[pp] = p[pp];
}

// ---------------------------------------------------------------------------
// K1: projection GEMM via bf16 MFMA: [bf16 xn](32768x256) @ [Wl|Wr](256x512)
// + bias, * row-mask -> bf16 L, R. 64 rows/block (4 waves x 16 rows), each
// wave covers all 32 n-tiles (acc = 128 VGPR). A staged via LDS (264-pad),
// B streamed in 32KB kb-chunks from pre-packed Wp2.
// ---------------------------------------------------------------------------
__global__ __launch_bounds__(256) void k_proj_mfma(
    const unsigned short* __restrict__ xn, const int* __restrict__ mask,
    const unsigned short* __restrict__ Wp2,
    const float* __restrict__ bl, const float* __restrict__ br,
    unsigned short* __restrict__ L, unsigned short* __restrict__ R)
{
    __shared__ __align__(16) unsigned short ash[64 * 264];   // 33792 B
    __shared__ float4 bsh[2048];                             // 32768 B
    const int tid = threadIdx.x;
    const int lane = tid & 63, wave = tid >> 6;
    const int quad = lane >> 4, mrow = lane & 15;
    const long r0 = (long)blockIdx.x * 64;

    // Stage A: 64 rows x 256 bf16, coalesced uint4 copies.
#pragma unroll
    for (int it = 0; it < 8; ++it) {
        const int c = tid + it * 256;
        const int row = c >> 5, col = (c & 31) * 8;
        *reinterpret_cast<uint4*>(&ash[row * 264 + col]) =
            *reinterpret_cast<const uint4*>(xn + (r0 + row) * 256 + col);
    }

    f32x4 acc[32];
#pragma unroll
    for (int nt = 0; nt < 32; ++nt) acc[nt] = {0.f, 0.f, 0.f, 0.f};

    const float4* wpv = reinterpret_cast<const float4*>(Wp2);
    const int arow = wave * 16 + mrow;

    for (int kb = 0; kb < 8; ++kb) {
        if (kb) __syncthreads();
#pragma unroll
        for (int it = 0; it < 8; ++it)
            bsh[tid + it * 256] = wpv[kb * 2048 + tid + it * 256];
        __syncthreads();

        const bf16x8 afr = *reinterpret_cast<const bf16x8*>(
            &ash[arow * 264 + kb * 32 + quad * 8]);
        const bf16x8* bptr = reinterpret_cast<const bf16x8*>(bsh);
#pragma unroll
        for (int nt = 0; nt < 32; ++nt) {
            bf16x8 b = bptr[nt * 64 + lane];
            acc[nt] = __builtin_amdgcn_mfma_f32_16x16x32_bf16(afr, b, acc[nt], 0, 0, 0);
        }
    }

    // Epilogue: C[row=quad*4+r][col=(nt&15)*16+mrow]; +bias, *mask, bf16 store.
    const long rowbase = r0 + wave * 16 + quad * 4;
    float mf[4];
#pragma unroll
    for (int r = 0; r < 4; ++r) mf[r] = mask[rowbase + r] ? 1.f : 0.f;

#pragma unroll
    for (int nt = 0; nt < 32; ++nt) {
        const int col = (nt & 15) * 16 + mrow;
        const float bias = (nt < 16) ? bl[col] : br[col];
        unsigned short* dst = (nt < 16) ? L : R;
#pragma unroll
        for (int r = 0; r < 4; ++r)
            dst[(rowbase + r) * 256 + col] =
                (unsigned short)f32_bf16((acc[nt][r] + bias) * mf[r]);
    }
}

// ---------------------------------------------------------------------------
// K2: outer[b,i,j,h] = scale[b,i,j] * sum_m L[b,m,i,h]*R[b,m,j,h]
// bf16 L/R inputs, fp32 accumulate, fp32 output staged in d_out.
// 8x8 (i,j) register tile per block, thread = h.
// ---------------------------------------------------------------------------
__global__ __launch_bounds__(256) void k_outer(
    const unsigned short* __restrict__ L, const unsigned short* __restrict__ R,
    const float* __restrict__ scale, float* __restrict__ outbuf)
{
    const int h = threadIdx.x;
    const int j0 = blockIdx.x * 8, i0 = blockIdx.y * 8, b = blockIdx.z;

    float acc[8][8];
#pragma unroll
    for (int ii = 0; ii < 8; ++ii)
#pragma unroll
        for (int jj = 0; jj < 8; ++jj) acc[ii][jj] = 0.f;

    const unsigned short* Lb = L + (size_t)b * (64 * 256 * 256);
    const unsigned short* Rb = R + (size_t)b * (64 * 256 * 256);

    for (int m = 0; m < 64; ++m) {
        const unsigned short* Lm = Lb + m * (256 * 256) + h;
        const unsigned short* Rm = Rb + m * (256 * 256) + h;
        float lv[8], rv[8];
#pragma unroll
        for (int ii = 0; ii < 8; ++ii) lv[ii] = bf16_f32(Lm[(i0 + ii) * 256]);
#pragma unroll
        for (int jj = 0; jj < 8; ++jj) rv[jj] = bf16_f32(Rm[(j0 + jj) * 256]);
#pragma unroll
        for (int ii = 0; ii < 8; ++ii)
#pragma unroll
            for (int jj = 0; jj < 8; ++jj)
                acc[ii][jj] += lv[ii] * rv[jj];
    }

#pragma unroll
    for (int ii = 0; ii < 8; ++ii) {
#pragma unroll
        for (int jj = 0; jj < 8; ++jj) {
            const int ij = (b * 256 + i0 + ii) * 256 + (j0 + jj);
            outbuf[(size_t)ij * 256 + h] = acc[ii][jj] * scale[ij];
        }
    }
}

// ---------------------------------------------------------------------------
// K3: in-place rows GEMM on d_out via bf16 MFMA: row <- bf16(row) @ bf16(Wo) + bo
// ---------------------------------------------------------------------------
__global__ __launch_bounds__(256) void k_wo_mfma(
    float* __restrict__ io, const unsigned short* __restrict__ Wp,
    const float* __restrict__ bo)
{
    __shared__ __align__(16) unsigned short ash[64 * 264];   // 33792 B
    __shared__ float4 bsh[1024];                             // 16384 B
    const int tid = threadIdx.x;
    const int lane = tid & 63, wave = tid >> 6;
    const int quad = lane >> 4, mrow = lane & 15;
    const long r0 = (long)blockIdx.x * 64;

    // Stage A: 64 rows x 256 fp32 -> bf16 LDS, coalesced.
#pragma unroll
    for (int it = 0; it < 8; ++it) {
        const int c = tid + it * 256;
        const int row = c >> 5, col = (c & 31) * 8;
        const float* src = io + (r0 + row) * 256 + col;
        const float4 a0 = *reinterpret_cast<const float4*>(src);
        const float4 a1 = *reinterpret_cast<const float4*>(src + 4);
        uint4 p;
        p.x = f32_bf16(a0.x) | (f32_bf16(a0.y) << 16);
        p.y = f32_bf16(a0.z) | (f32_bf16(a0.w) << 16);
        p.z = f32_bf16(a1.x) | (f32_bf16(a1.y) << 16);
        p.w = f32_bf16(a1.z) | (f32_bf16(a1.w) << 16);
        *reinterpret_cast<uint4*>(&ash[row * 264 + col]) = p;
    }

    f32x4 acc[16];
#pragma unroll
    for (int nt = 0; nt < 16; ++nt) acc[nt] = {0.f, 0.f, 0.f, 0.f};

    const float4* wpv = reinterpret_cast<const float4*>(Wp);
    const int arow = wave * 16 + mrow;

    for (int kb = 0; kb < 8; ++kb) {
        if (kb) __syncthreads();
#pragma unroll
        for (int it = 0; it < 4; ++it)
            bsh[tid + it * 256] = wpv[kb * 1024 + tid + it * 256];
        __syncthreads();

        const bf16x8 afr = *reinterpret_cast<const bf16x8*>(
            &ash[arow * 264 + kb * 32 + quad * 8]);
        const bf16x8* bptr = reinterpret_cast<const bf16x8*>(bsh);
#pragma unroll
        for (int nt = 0; nt < 16; ++nt) {
            bf16x8 b = bptr[nt * 64 + lane];
            acc[nt] = __builtin_amdgcn_mfma_f32_16x16x32_bf16(afr, b, acc[nt], 0, 0, 0);
        }
    }

#pragma unroll
    for (int nt = 0; nt < 16; ++nt) {
        const int col = nt * 16 + mrow;
        const float bov = bo[col];
#pragma unroll
        for (int r = 0; r < 4; ++r)
            io[(r0 + wave * 16 + quad * 4 + r) * 256 + col] = acc[nt][r] + bov;
    }
}

// ---------------------------------------------------------------------------
extern "C" void kernel_launch(void* const* d_in, const int* in_sizes, int n_in,
                              void* d_out, int out_size, void* d_ws, size_t ws_size,
                              hipStream_t stream)
{
    const float* x    = (const float*)d_in[0];
    const int*   mask = (const int*)  d_in[1];
    const float* ln_w = (const float*)d_in[2];
    const float* ln_b = (const float*)d_in[3];
    const float* Wl   = (const float*)d_in[4];
    const float* bl   = (const float*)d_in[5];
    const float* Wr   = (const float*)d_in[6];
    const float* br   = (const float*)d_in[7];
    const float* Wo   = (const float*)d_in[8];
    const float* bo   = (const float*)d_in[9];

    float* out = (float*)d_out;
    char*  ws  = (char*)d_ws;
    unsigned short* xn    = (unsigned short*)(ws);                     // 16 MB
    unsigned short* L     = (unsigned short*)(ws + 16777216);          // 16 MB
    unsigned short* R     = (unsigned short*)(ws + 33554432);          // 16 MB
    float*          scale = (float*)         (ws + 50331648);          // 512 KB
    unsigned short* Wp    = (unsigned short*)(ws + 50855936);          // 128 KB (Wo)
    unsigned short* Wp2   = (unsigned short*)(ws + 50987008);          // 256 KB (Wl|Wr)

    k_ln<<<4096, 256, 0, stream>>>(x, ln_w, ln_b, xn);
    k_pack_wlr<<<64, 256, 0, stream>>>(Wl, Wr, Wp2);
    k_pack_wo<<<32, 256, 0, stream>>>(Wo, Wp);
    k_cnt<<<dim3(256, 2), 256, 0, stream>>>(mask, scale);
    k_proj_mfma<<<512, 256, 0, stream>>>(xn, mask, Wp2, bl, br, L, R);
    k_outer<<<dim3(32, 32, 2), 256, 0, stream>>>(L, R, scale, out);
    k_wo_mfma<<<2048, 256, 0, stream>>>(out, Wp, bo);
}